// Round 3
// baseline (293.295 us; speedup 1.0000x reference)
//
#include <hip/hip_runtime.h>

#define B_ 8
#define L_ 2048
#define E_ 256
#define H_ 4
#define D_ 64

typedef __bf16 bf16;
typedef __bf16 bf16x8 __attribute__((ext_vector_type(8)));
typedef __bf16 bf16x4 __attribute__((ext_vector_type(4)));
typedef float  f32x4  __attribute__((ext_vector_type(4)));
typedef float  f32x8  __attribute__((ext_vector_type(8)));
typedef float  f32x16 __attribute__((ext_vector_type(16)));

// Ŝ = (q·k)/8 * log2(e); softmax entirely in exp2 domain.
#define QSCALE 0.1803368801111244f

__device__ __forceinline__ float fexp2(float x) { return __builtin_amdgcn_exp2f(x); }
__device__ __forceinline__ float flog2(float x) { return __builtin_amdgcn_logf(x); }

// ---------------------------------------------------------------------------
// Kernel 1: repack weights to bf16.
// Wcat[768][256]: rows 0..511 = in_proj_w rows (q,k); rows 512..767 = W_gnn^T
// ---------------------------------------------------------------------------
__global__ void prep_weights(const float* __restrict__ in_proj_w,
                             const float* __restrict__ W_gnn,
                             bf16* __restrict__ Wcat) {
    int r = blockIdx.x;
    int e = threadIdx.x;
    float v = (r < 512) ? in_proj_w[r * E_ + e] : W_gnn[e * E_ + (r - 512)];
    Wcat[r * E_ + e] = (bf16)v;
}

// ---------------------------------------------------------------------------
// Kernel 2: projections. C[M=16384, N=768] = x @ Wcat^T (bf16 MFMA, fp32 acc)
//   by==0 -> Qs[B,L,E]  (bias + QSCALE folded; col n = h*64+d)
//   by==1 -> Ks[B,L,E]  (bias folded)
//   by==2 -> XWT[B,E,L] = (x @ W_gnn + B_gnn)^T per batch, bf16
// ---------------------------------------------------------------------------
__global__ __launch_bounds__(256, 2) void proj_kernel(
    const float* __restrict__ x, const bf16* __restrict__ Wcat,
    const float* __restrict__ in_proj_b, const float* __restrict__ B_gnn,
    bf16* __restrict__ Qs, bf16* __restrict__ Ks, bf16* __restrict__ XWT) {
    int tid  = threadIdx.x;
    int lane = tid & 63, wave = tid >> 6;
    int l16  = lane & 15, quad = lane >> 4;
    int m0 = blockIdx.x * 64 + wave * 16;
    int by = blockIdx.y;
    int n0 = by * 256;

    f32x4 acc[16];
#pragma unroll
    for (int i = 0; i < 16; i++) acc[i] = (f32x4){0.f, 0.f, 0.f, 0.f};

    const float* xrow = x + (size_t)(m0 + l16) * E_;
    for (int ks = 0; ks < 8; ks++) {
        int koff = ks * 32 + quad * 8;
        f32x8 av = *(const f32x8*)&xrow[koff];
        bf16x8 af;
#pragma unroll
        for (int j = 0; j < 8; j++) af[j] = (bf16)av[j];
#pragma unroll
        for (int nt = 0; nt < 16; nt++) {
            bf16x8 bfv = *(const bf16x8*)&Wcat[(size_t)(n0 + nt * 16 + l16) * E_ + koff];
            acc[nt] = __builtin_amdgcn_mfma_f32_16x16x32_bf16(af, bfv, acc[nt], 0, 0, 0);
        }
    }

#pragma unroll
    for (int nt = 0; nt < 16; nt++) {
        int n = n0 + nt * 16 + l16;
        if (by == 0) {
            float bias = in_proj_b[n];
#pragma unroll
            for (int r = 0; r < 4; r++) {
                int m = m0 + quad * 4 + r;
                Qs[(size_t)m * E_ + n] = (bf16)((acc[nt][r] + bias) * QSCALE);
            }
        } else if (by == 1) {
            float bias = in_proj_b[n];
            int col = n - 256;
#pragma unroll
            for (int r = 0; r < 4; r++) {
                int m = m0 + quad * 4 + r;
                Ks[(size_t)m * E_ + col] = (bf16)(acc[nt][r] + bias);
            }
        } else {
            int nc = n - 512;
            float bias = B_gnn[nc];
            int m = m0 + quad * 4;
            int b = m >> 11, l = m & 2047;
            bf16x4 pk;
#pragma unroll
            for (int r = 0; r < 4; r++) pk[r] = (bf16)(acc[nt][r] + bias);
            *(bf16x4*)&XWT[((size_t)b * E_ + nc) * L_ + l] = pk;
        }
    }
}

// ---------------------------------------------------------------------------
// Kernel 3: softmax stats. o[b,h,q] = -log2(4 * sum_k exp2(Shat)).
// ---------------------------------------------------------------------------
__global__ __launch_bounds__(256, 4) void stats_kernel(
    const bf16* __restrict__ Qs, const bf16* __restrict__ Ks,
    float* __restrict__ o) {
    __shared__ bf16 ldsK[64 * 72];
    int tid  = threadIdx.x;
    int lane = tid & 63, wave = tid >> 6;
    int r32  = lane & 31, half = lane >> 5;
    int qt = blockIdx.x, h = blockIdx.y, b = blockIdx.z;
    int q0 = qt * 128 + wave * 32;

    bf16x8 qa[4];
    const bf16* qrow = Qs + ((size_t)b * L_ + q0 + r32) * E_ + h * D_;
#pragma unroll
    for (int c = 0; c < 4; c++) qa[c] = *(const bf16x8*)&qrow[c * 16 + half * 8];

    float lsum[16];
#pragma unroll
    for (int i = 0; i < 16; i++) lsum[i] = 0.f;

    const bf16* Kb = Ks + (size_t)b * L_ * E_ + h * D_;
    for (int kt = 0; kt < 32; kt++) {
        __syncthreads();
#pragma unroll
        for (int it = 0; it < 2; it++) {
            int idx = it * 256 + tid;
            int key = idx >> 3, dc = (idx & 7) * 8;
            *(bf16x8*)&ldsK[key * 72 + dc] =
                *(const bf16x8*)&Kb[(size_t)(kt * 64 + key) * E_ + dc];
        }
        __syncthreads();
#pragma unroll
        for (int nt = 0; nt < 2; nt++) {
            f32x16 S = {};
#pragma unroll
            for (int c = 0; c < 4; c++) {
                bf16x8 kb = *(const bf16x8*)&ldsK[(nt * 32 + r32) * 72 + c * 16 + half * 8];
                S = __builtin_amdgcn_mfma_f32_32x32x16_bf16(qa[c], kb, S, 0, 0, 0);
            }
#pragma unroll
            for (int i = 0; i < 16; i++) lsum[i] += fexp2(S[i]);
        }
    }
#pragma unroll
    for (int i = 0; i < 16; i++) {
        float v = lsum[i];
        v += __shfl_xor(v, 1); v += __shfl_xor(v, 2); v += __shfl_xor(v, 4);
        v += __shfl_xor(v, 8); v += __shfl_xor(v, 16);
        lsum[i] = v;
    }
    if (r32 == 0) {
        float* op = o + ((size_t)(b * H_ + h)) * L_ + q0;
#pragma unroll
        for (int i = 0; i < 16; i++) {
            int row = (i & 3) + 8 * (i >> 2) + 4 * half;
            op[row] = -(2.0f + flog2(lsum[i]));
        }
    }
}

// ---------------------------------------------------------------------------
// Kernel 4: pass 2. 32 q rows per wave (two 16-row subtiles sharing all
// B-fragment LDS reads) -> LDS bytes per MFMA FLOP halved vs 16 q/wave.
// ksp=4 k-splits keep 512 blocks = 2/CU. o table in LDS (broadcast reads),
// Q frags re-read per head from L2 -> VGPR peak < 256. bf16 partials.
// ---------------------------------------------------------------------------
__global__ __launch_bounds__(256, 2) void pass2_kernel(
    const bf16* __restrict__ Qs, const bf16* __restrict__ Ks,
    const bf16* __restrict__ XWT, const float* __restrict__ o,
    bf16* __restrict__ Opart) {
    __shared__ bf16 ldsK[64 * 264];    // [64 keys][256 E + 8 pad]   33792 B
    __shared__ bf16 ldsXW[256 * 72];   // [256 n][64 k + 8 pad]      36864 B
    __shared__ bf16 ldsP[64 * 72];     // per-wave 16-row region      9216 B
    __shared__ float ldsO[4 * 128];    // o[h][qi] for this block     2048 B
                                       // total = 81920 B = 2 blocks/CU

    int tid  = threadIdx.x;
    int lane = tid & 63, wave = tid >> 6;
    int l16  = lane & 15, quad = lane >> 4;
    int qt = blockIdx.x, ksp = blockIdx.y, b = blockIdx.z;
    int q0 = qt * 128 + wave * 32;

    // stage o table: 512 f32
#pragma unroll
    for (int j = tid; j < 512; j += 256) {
        int h_ = j >> 7, i_ = j & 127;
        ldsO[j] = o[((size_t)(b * H_ + h_)) * L_ + qt * 128 + i_];
    }

    const bf16* qp0 = Qs + ((size_t)b * L_ + q0 + l16) * E_;
    const bf16* qp1 = qp0 + (size_t)16 * E_;

    f32x4 acc[2][16];
#pragma unroll
    for (int s = 0; s < 2; s++)
#pragma unroll
        for (int i = 0; i < 16; i++) acc[s][i] = (f32x4){0.f, 0.f, 0.f, 0.f};

    const bf16* Kb = Ks + (size_t)b * L_ * E_;
    const bf16* Xb = XWT + (size_t)b * E_ * L_;

    for (int kt = 0; kt < 8; kt++) {
        int k0 = ksp * 512 + kt * 64;
        __syncthreads();
#pragma unroll
        for (int it = 0; it < 8; it++) {
            int idx = it * 256 + tid;
            int key = idx >> 5, col = (idx & 31) * 8;
            *(bf16x8*)&ldsK[key * 264 + col] =
                *(const bf16x8*)&Kb[(size_t)(k0 + key) * E_ + col];
        }
#pragma unroll
        for (int it = 0; it < 8; it++) {
            int idx = it * 256 + tid;
            int n = idx >> 3, kc = (idx & 7) * 8;
            *(bf16x8*)&ldsXW[n * 72 + kc] =
                *(const bf16x8*)&Xb[(size_t)n * L_ + k0 + kc];
        }
        __syncthreads();

        // P[s] = sum_h exp2(Shat_h + o_h), q-subtiles s=0,1 share K frags
        f32x4 P[2][4];
#pragma unroll
        for (int s = 0; s < 2; s++)
#pragma unroll
            for (int nt = 0; nt < 4; nt++) P[s][nt] = (f32x4){0.f, 0.f, 0.f, 0.f};

        for (int h = 0; h < H_; h++) {
            // Q frags for this head (L2-hot re-read; keeps VGPR peak low)
            bf16x8 qc[2][2];
            qc[0][0] = *(const bf16x8*)&qp0[h * 64 + quad * 8];
            qc[0][1] = *(const bf16x8*)&qp0[h * 64 + 32 + quad * 8];
            qc[1][0] = *(const bf16x8*)&qp1[h * 64 + quad * 8];
            qc[1][1] = *(const bf16x8*)&qp1[h * 64 + 32 + quad * 8];

            f32x4 S[2][4];
#pragma unroll
            for (int s = 0; s < 2; s++)
#pragma unroll
                for (int nt = 0; nt < 4; nt++) S[s][nt] = (f32x4){0.f, 0.f, 0.f, 0.f};
#pragma unroll
            for (int nt = 0; nt < 4; nt++) {
                bf16x8 k0f = *(const bf16x8*)&ldsK[(nt * 16 + l16) * 264 + h * 64 + quad * 8];
                bf16x8 k1f = *(const bf16x8*)&ldsK[(nt * 16 + l16) * 264 + h * 64 + 32 + quad * 8];
#pragma unroll
                for (int s = 0; s < 2; s++) {
                    S[s][nt] = __builtin_amdgcn_mfma_f32_16x16x32_bf16(qc[s][0], k0f, S[s][nt], 0, 0, 0);
                    S[s][nt] = __builtin_amdgcn_mfma_f32_16x16x32_bf16(qc[s][1], k1f, S[s][nt], 0, 0, 0);
                }
            }
#pragma unroll
            for (int s = 0; s < 2; s++)
#pragma unroll
                for (int r = 0; r < 4; r++) {
                    float off = ldsO[h * 128 + wave * 32 + s * 16 + quad * 4 + r];
#pragma unroll
                    for (int nt = 0; nt < 4; nt++)
                        P[s][nt][r] += fexp2(S[s][nt][r] + off);
                }
        }

        // P transpose (C->A layout) per subtile, reusing per-wave ldsP region
        bf16x8 pf[2][2];
#pragma unroll
        for (int s = 0; s < 2; s++) {
#pragma unroll
            for (int nt = 0; nt < 4; nt++)
#pragma unroll
                for (int r = 0; r < 4; r++)
                    ldsP[(wave * 16 + quad * 4 + r) * 72 + nt * 16 + l16] = (bf16)P[s][nt][r];
            pf[s][0] = *(const bf16x8*)&ldsP[(wave * 16 + l16) * 72 + quad * 8];
            pf[s][1] = *(const bf16x8*)&ldsP[(wave * 16 + l16) * 72 + 32 + quad * 8];
        }

        // PV: both subtiles share XW frags
#pragma unroll
        for (int nt = 0; nt < 16; nt++) {
            bf16x8 b0 = *(const bf16x8*)&ldsXW[(nt * 16 + l16) * 72 + quad * 8];
            bf16x8 b1 = *(const bf16x8*)&ldsXW[(nt * 16 + l16) * 72 + 32 + quad * 8];
#pragma unroll
            for (int s = 0; s < 2; s++) {
                acc[s][nt] = __builtin_amdgcn_mfma_f32_16x16x32_bf16(pf[s][0], b0, acc[s][nt], 0, 0, 0);
                acc[s][nt] = __builtin_amdgcn_mfma_f32_16x16x32_bf16(pf[s][1], b1, acc[s][nt], 0, 0, 0);
            }
        }
    }

    bf16* Ob = Opart + ((size_t)(ksp * B_ + b)) * L_ * E_ + (size_t)q0 * E_;
#pragma unroll
    for (int s = 0; s < 2; s++)
#pragma unroll
        for (int nt = 0; nt < 16; nt++)
#pragma unroll
            for (int r = 0; r < 4; r++)
                Ob[(size_t)(s * 16 + quad * 4 + r) * E_ + nt * 16 + l16] = (bf16)acc[s][nt][r];
}

// ---------------------------------------------------------------------------
// Kernel 5: sum the 4 k-split bf16 partials -> fp32 out[B,L,E]
// ---------------------------------------------------------------------------
__global__ void reduce_kernel(const bf16* __restrict__ Op, float* __restrict__ out) {
    size_t i = ((size_t)blockIdx.x * 256 + threadIdx.x) * 8;
    const size_t BLE = (size_t)B_ * L_ * E_;
    float s[8];
#pragma unroll
    for (int j = 0; j < 8; j++) s[j] = 0.f;
#pragma unroll
    for (int p = 0; p < 4; p++) {
        bf16x8 v = *(const bf16x8*)&Op[p * BLE + i];
#pragma unroll
        for (int j = 0; j < 8; j++) s[j] += (float)v[j];
    }
    f32x4 o0 = {s[0], s[1], s[2], s[3]}, o1 = {s[4], s[5], s[6], s[7]};
    *(f32x4*)&out[i] = o0;
    *(f32x4*)&out[i + 4] = o1;
}

// ---------------------------------------------------------------------------
extern "C" void kernel_launch(void* const* d_in, const int* in_sizes, int n_in,
                              void* d_out, int out_size, void* d_ws, size_t ws_size,
                              hipStream_t stream) {
    const float* x   = (const float*)d_in[0];
    const float* ipw = (const float*)d_in[1];
    const float* ipb = (const float*)d_in[2];
    const float* wg  = (const float*)d_in[3];
    const float* bg  = (const float*)d_in[4];

    char* ws = (char*)d_ws;
    // ws layout (bytes), total 58,982,400:
    //   Qs    [B,L,E]   bf16 @ 0          (8,388,608)
    //   Ks    [B,L,E]   bf16 @ 8388608    (8,388,608)
    //   XWT   [B,E,L]   bf16 @ 16777216   (8,388,608)
    //   o     [B,H,L]   f32  @ 25165824   (  262,144)
    //   Opart [4,B,L,E] bf16 @ 25427968   (33,554,432)
    //   Wcat  [768,256] bf16 @ 25427968   (overlaps Opart; dead before pass2)
    bf16*  Qs    = (bf16*)(ws);
    bf16*  Ks    = (bf16*)(ws + 8388608);
    bf16*  XWT   = (bf16*)(ws + 16777216);
    float* o     = (float*)(ws + 25165824);
    bf16*  Opart = (bf16*)(ws + 25427968);
    bf16*  Wcat  = (bf16*)(ws + 25427968);

    prep_weights<<<768, 256, 0, stream>>>(ipw, wg, Wcat);
    proj_kernel<<<dim3(256, 3), 256, 0, stream>>>(x, Wcat, ipb, bg, Qs, Ks, XWT);
    stats_kernel<<<dim3(16, 4, 8), 256, 0, stream>>>(Qs, Ks, o);
    pass2_kernel<<<dim3(16, 4, 8), 256, 0, stream>>>(Qs, Ks, XWT, o, Opart);
    reduce_kernel<<<2048, 256, 0, stream>>>(Opart, (float*)d_out);
}

// Round 4
// 253.602 us; speedup vs baseline: 1.1565x; 1.1565x over previous
//
#include <hip/hip_runtime.h>

#define B_ 8
#define L_ 2048
#define E_ 256
#define H_ 4
#define D_ 64

typedef __bf16 bf16;
typedef __bf16 bf16x8 __attribute__((ext_vector_type(8)));
typedef __bf16 bf16x4 __attribute__((ext_vector_type(4)));
typedef float  f32x4  __attribute__((ext_vector_type(4)));
typedef float  f32x8  __attribute__((ext_vector_type(8)));
typedef float  f32x16 __attribute__((ext_vector_type(16)));

// Shat = (q.k)/8 * log2(e); softmax entirely in exp2 domain.
#define QSCALE 0.1803368801111244f

__device__ __forceinline__ float fexp2(float x) { return __builtin_amdgcn_exp2f(x); }
__device__ __forceinline__ float flog2(float x) { return __builtin_amdgcn_logf(x); }

// ---------------------------------------------------------------------------
// Kernel 1: repack weights to bf16.
// Wcat[768][256]: rows 0..511 = in_proj_w rows (q,k); rows 512..767 = W_gnn^T
// ---------------------------------------------------------------------------
__global__ void prep_weights(const float* __restrict__ in_proj_w,
                             const float* __restrict__ W_gnn,
                             bf16* __restrict__ Wcat) {
    int r = blockIdx.x;
    int e = threadIdx.x;
    float v = (r < 512) ? in_proj_w[r * E_ + e] : W_gnn[e * E_ + (r - 512)];
    Wcat[r * E_ + e] = (bf16)v;
}

// ---------------------------------------------------------------------------
// Kernel 2: projections. 256 blocks (1/CU); each block owns 64 x-rows and
// loops by=0,1,2 internally so x is fetched from HBM ONCE (L1/L2-hot on
// by=1,2), vs 3x in the grid-split version.
//   by==0 -> Qs[B,L,E]  (bias + QSCALE folded; col n = h*64+d)
//   by==1 -> Ks[B,L,E]  (bias folded)
//   by==2 -> XWT[B,E,L] = (x @ W_gnn + B_gnn)^T per batch, bf16
// ---------------------------------------------------------------------------
__global__ __launch_bounds__(256, 1) void proj_kernel(
    const float* __restrict__ x, const bf16* __restrict__ Wcat,
    const float* __restrict__ in_proj_b, const float* __restrict__ B_gnn,
    bf16* __restrict__ Qs, bf16* __restrict__ Ks, bf16* __restrict__ XWT) {
    int tid  = threadIdx.x;
    int lane = tid & 63, wave = tid >> 6;
    int l16  = lane & 15, quad = lane >> 4;
    int m0 = blockIdx.x * 64 + wave * 16;

    const float* xrow = x + (size_t)(m0 + l16) * E_;

    for (int by = 0; by < 3; by++) {
        int n0 = by * 256;
        f32x4 acc[16];
#pragma unroll
        for (int i = 0; i < 16; i++) acc[i] = (f32x4){0.f, 0.f, 0.f, 0.f};

        for (int ks = 0; ks < 8; ks++) {
            int koff = ks * 32 + quad * 8;
            f32x8 av = *(const f32x8*)&xrow[koff];
            bf16x8 af;
#pragma unroll
            for (int j = 0; j < 8; j++) af[j] = (bf16)av[j];
#pragma unroll
            for (int nt = 0; nt < 16; nt++) {
                bf16x8 bfv = *(const bf16x8*)&Wcat[(size_t)(n0 + nt * 16 + l16) * E_ + koff];
                acc[nt] = __builtin_amdgcn_mfma_f32_16x16x32_bf16(af, bfv, acc[nt], 0, 0, 0);
            }
        }

#pragma unroll
        for (int nt = 0; nt < 16; nt++) {
            int n = n0 + nt * 16 + l16;
            if (by == 0) {
                float bias = in_proj_b[n];
#pragma unroll
                for (int r = 0; r < 4; r++) {
                    int m = m0 + quad * 4 + r;
                    Qs[(size_t)m * E_ + n] = (bf16)((acc[nt][r] + bias) * QSCALE);
                }
            } else if (by == 1) {
                float bias = in_proj_b[n];
                int col = n - 256;
#pragma unroll
                for (int r = 0; r < 4; r++) {
                    int m = m0 + quad * 4 + r;
                    Ks[(size_t)m * E_ + col] = (bf16)(acc[nt][r] + bias);
                }
            } else {
                int nc = n - 512;
                float bias = B_gnn[nc];
                int m = m0 + quad * 4;
                int b = m >> 11, l = m & 2047;
                bf16x4 pk;
#pragma unroll
                for (int r = 0; r < 4; r++) pk[r] = (bf16)(acc[nt][r] + bias);
                *(bf16x4*)&XWT[((size_t)b * E_ + nc) * L_ + l] = pk;
            }
        }
    }
}

// ---------------------------------------------------------------------------
// Kernel 3: softmax stats. o[b,h,q] = -log2(4 * sum_k exp2(Shat)).
// 64 q rows per wave (2 q-groups share every K B-frag read) -> LDS:MFMA
// ratio halved vs R2. 256 blocks (1/CU); staging prefetched into regs.
// 32x32x16 C/D: col=lane&31, row=(reg&3)+8*(reg>>2)+4*(lane>>5).
// ---------------------------------------------------------------------------
__global__ __launch_bounds__(256, 1) void stats_kernel(
    const bf16* __restrict__ Qs, const bf16* __restrict__ Ks,
    float* __restrict__ o) {
    __shared__ bf16 ldsK[64 * 72];
    int tid  = threadIdx.x;
    int lane = tid & 63, wave = tid >> 6;
    int r32  = lane & 31, half = lane >> 5;
    int qt = blockIdx.x, h = blockIdx.y, b = blockIdx.z;
    int q0 = qt * 256 + wave * 64;

    // A frags: 2 q-groups x 4 k-chunks (m=r32 within group, k=c*16+half*8+j)
    bf16x8 qa[2][4];
#pragma unroll
    for (int g = 0; g < 2; g++) {
        const bf16* qrow = Qs + ((size_t)b * L_ + q0 + g * 32 + r32) * E_ + h * D_;
#pragma unroll
        for (int c = 0; c < 4; c++) qa[g][c] = *(const bf16x8*)&qrow[c * 16 + half * 8];
    }

    float lsum[2][16];
#pragma unroll
    for (int g = 0; g < 2; g++)
#pragma unroll
        for (int i = 0; i < 16; i++) lsum[g][i] = 0.f;

    const bf16* Kb = Ks + (size_t)b * L_ * E_ + h * D_;

    // prologue: stage tile 0
    bf16x8 pre[2];
#pragma unroll
    for (int it = 0; it < 2; it++) {
        int idx = it * 256 + tid;
        int key = idx >> 3, dc = (idx & 7) * 8;
        pre[it] = *(const bf16x8*)&Kb[(size_t)key * E_ + dc];
    }
#pragma unroll
    for (int it = 0; it < 2; it++) {
        int idx = it * 256 + tid;
        int key = idx >> 3, dc = (idx & 7) * 8;
        *(bf16x8*)&ldsK[key * 72 + dc] = pre[it];
    }
    __syncthreads();

    for (int kt = 0; kt < 32; kt++) {
        // prefetch next tile into regs (latency hidden behind compute)
        if (kt < 31) {
#pragma unroll
            for (int it = 0; it < 2; it++) {
                int idx = it * 256 + tid;
                int key = idx >> 3, dc = (idx & 7) * 8;
                pre[it] = *(const bf16x8*)&Kb[(size_t)((kt + 1) * 64 + key) * E_ + dc];
            }
        }
#pragma unroll
        for (int nt = 0; nt < 2; nt++) {
            bf16x8 kb[4];
#pragma unroll
            for (int c = 0; c < 4; c++)
                kb[c] = *(const bf16x8*)&ldsK[(nt * 32 + r32) * 72 + c * 16 + half * 8];
#pragma unroll
            for (int g = 0; g < 2; g++) {
                f32x16 S = {};
#pragma unroll
                for (int c = 0; c < 4; c++)
                    S = __builtin_amdgcn_mfma_f32_32x32x16_bf16(qa[g][c], kb[c], S, 0, 0, 0);
#pragma unroll
                for (int i = 0; i < 16; i++) lsum[g][i] += fexp2(S[i]);
            }
        }
        __syncthreads();
        if (kt < 31) {
#pragma unroll
            for (int it = 0; it < 2; it++) {
                int idx = it * 256 + tid;
                int key = idx >> 3, dc = (idx & 7) * 8;
                *(bf16x8*)&ldsK[key * 72 + dc] = pre[it];
            }
        }
        __syncthreads();
    }

#pragma unroll
    for (int g = 0; g < 2; g++)
#pragma unroll
        for (int i = 0; i < 16; i++) {
            float v = lsum[g][i];
            v += __shfl_xor(v, 1); v += __shfl_xor(v, 2); v += __shfl_xor(v, 4);
            v += __shfl_xor(v, 8); v += __shfl_xor(v, 16);
            lsum[g][i] = v;
        }
    if (r32 == 0) {
        float* op = o + ((size_t)(b * H_ + h)) * L_ + q0;
#pragma unroll
        for (int g = 0; g < 2; g++)
#pragma unroll
            for (int i = 0; i < 16; i++) {
                int row = g * 32 + (i & 3) + 8 * (i >> 2) + 4 * half;
                op[row] = -(2.0f + flog2(lsum[g][i]));
            }
    }
}

// ---------------------------------------------------------------------------
// Kernel 4: pass 2. 256 blocks (1/CU), __launch_bounds__(256,1) -> 512-reg
// budget: Q frags for all 4 heads+2 subtiles in VGPRs (fixes R3's 229 MB
// L2-thrash), staging register-prefetched (hides HBM latency lost to 1
// wave/SIMD). PV operand-swapped: A=XW, B=P^T (same LDS reads, b64 stores).
// bf16 partials, ksp=2.
// ---------------------------------------------------------------------------
__global__ __launch_bounds__(256, 1) void pass2_kernel(
    const bf16* __restrict__ Qs, const bf16* __restrict__ Ks,
    const bf16* __restrict__ XWT, const float* __restrict__ o,
    bf16* __restrict__ Opart) {
    __shared__ bf16 ldsK[64 * 264];      // [64 keys][256 E + 8 pad]   33792 B
    __shared__ bf16 ldsXW[256 * 72];     // [256 n][64 k + 8 pad]      36864 B
    __shared__ bf16 ldsP[4][32 * 72];    // per-wave [32 q][64 k + 8]  18432 B
    __shared__ float ldsO[4 * 128];      //                             2048 B  -> 91136 B total

    int tid  = threadIdx.x;
    int lane = tid & 63, wave = tid >> 6;
    int l16  = lane & 15, quad = lane >> 4;
    int qt = blockIdx.x, ksp = blockIdx.y, b = blockIdx.z;
    int q0 = qt * 128 + wave * 32;

#pragma unroll
    for (int j = tid; j < 512; j += 256) {
        int h_ = j >> 7, i_ = j & 127;
        ldsO[j] = o[((size_t)(b * H_ + h_)) * L_ + qt * 128 + i_];
    }

    // Q fragments: [subtile][head][frag] -- resident whole kernel (64 VGPR)
    bf16x8 qf[2][4][2];
    const bf16* qp = Qs + ((size_t)b * L_ + q0 + l16) * E_;
#pragma unroll
    for (int s = 0; s < 2; s++)
#pragma unroll
        for (int h = 0; h < H_; h++) {
            qf[s][h][0] = *(const bf16x8*)&qp[(size_t)s * 16 * E_ + h * 64 + quad * 8];
            qf[s][h][1] = *(const bf16x8*)&qp[(size_t)s * 16 * E_ + h * 64 + 32 + quad * 8];
        }

    f32x4 acc[2][16];
#pragma unroll
    for (int s = 0; s < 2; s++)
#pragma unroll
        for (int i = 0; i < 16; i++) acc[s][i] = (f32x4){0.f, 0.f, 0.f, 0.f};

    const bf16* Kb = Ks + (size_t)b * L_ * E_;
    const bf16* Xb = XWT + (size_t)b * E_ * L_;
    int kbase = ksp * 1024;

    // prologue: stage tile 0
    bf16x8 preK[8], preX[8];
#pragma unroll
    for (int it = 0; it < 8; it++) {
        int idx = it * 256 + tid;
        int key = idx >> 5, col = (idx & 31) * 8;
        preK[it] = *(const bf16x8*)&Kb[(size_t)(kbase + key) * E_ + col];
        int n = idx >> 3, kc = (idx & 7) * 8;
        preX[it] = *(const bf16x8*)&Xb[(size_t)n * L_ + kbase + kc];
    }
#pragma unroll
    for (int it = 0; it < 8; it++) {
        int idx = it * 256 + tid;
        int key = idx >> 5, col = (idx & 31) * 8;
        *(bf16x8*)&ldsK[key * 264 + col] = preK[it];
        int n = idx >> 3, kc = (idx & 7) * 8;
        *(bf16x8*)&ldsXW[n * 72 + kc] = preX[it];
    }
    __syncthreads();

    for (int kt = 0; kt < 16; kt++) {
        // prefetch tile kt+1 into regs
        if (kt < 15) {
            int k0n = kbase + (kt + 1) * 64;
#pragma unroll
            for (int it = 0; it < 8; it++) {
                int idx = it * 256 + tid;
                int key = idx >> 5, col = (idx & 31) * 8;
                preK[it] = *(const bf16x8*)&Kb[(size_t)(k0n + key) * E_ + col];
                int n = idx >> 3, kc = (idx & 7) * 8;
                preX[it] = *(const bf16x8*)&Xb[(size_t)n * L_ + k0n + kc];
            }
        }

        // QK + exp2 -> P (P = sum_h exp2(Shat_h + o_h))
        f32x4 P[2][4];
#pragma unroll
        for (int s = 0; s < 2; s++)
#pragma unroll
            for (int nt = 0; nt < 4; nt++) P[s][nt] = (f32x4){0.f, 0.f, 0.f, 0.f};

#pragma unroll
        for (int h = 0; h < H_; h++) {
            f32x4 S[2][4];
#pragma unroll
            for (int s = 0; s < 2; s++)
#pragma unroll
                for (int nt = 0; nt < 4; nt++) S[s][nt] = (f32x4){0.f, 0.f, 0.f, 0.f};
#pragma unroll
            for (int nt = 0; nt < 4; nt++) {
                bf16x8 k0f = *(const bf16x8*)&ldsK[(nt * 16 + l16) * 264 + h * 64 + quad * 8];
                bf16x8 k1f = *(const bf16x8*)&ldsK[(nt * 16 + l16) * 264 + h * 64 + 32 + quad * 8];
#pragma unroll
                for (int s = 0; s < 2; s++) {
                    S[s][nt] = __builtin_amdgcn_mfma_f32_16x16x32_bf16(qf[s][h][0], k0f, S[s][nt], 0, 0, 0);
                    S[s][nt] = __builtin_amdgcn_mfma_f32_16x16x32_bf16(qf[s][h][1], k1f, S[s][nt], 0, 0, 0);
                }
            }
#pragma unroll
            for (int s = 0; s < 2; s++)
#pragma unroll
                for (int r = 0; r < 4; r++) {
                    float off = ldsO[h * 128 + wave * 32 + s * 16 + quad * 4 + r];
#pragma unroll
                    for (int nt = 0; nt < 4; nt++)
                        P[s][nt][r] += fexp2(S[s][nt][r] + off);
                }
        }

        // P -> per-wave LDS (rows = s*16+quad*4+r, cols = nt*16+l16)
#pragma unroll
        for (int s = 0; s < 2; s++)
#pragma unroll
            for (int nt = 0; nt < 4; nt++)
#pragma unroll
                for (int r = 0; r < 4; r++)
                    ldsP[wave][(s * 16 + quad * 4 + r) * 72 + nt * 16 + l16] = (bf16)P[s][nt][r];

        // B-frags of P^T (lane q=l16, k=quad*8+j -> row-major b128)
        bf16x8 pf[2][2];
#pragma unroll
        for (int s = 0; s < 2; s++) {
            pf[s][0] = *(const bf16x8*)&ldsP[wave][(s * 16 + l16) * 72 + quad * 8];
            pf[s][1] = *(const bf16x8*)&ldsP[wave][(s * 16 + l16) * 72 + 32 + quad * 8];
        }

        // PV (swapped): D[n][q] = sum_k XW[n][k] * P[q][k]
#pragma unroll
        for (int nt = 0; nt < 16; nt++) {
            bf16x8 a0 = *(const bf16x8*)&ldsXW[(nt * 16 + l16) * 72 + quad * 8];
            bf16x8 a1 = *(const bf16x8*)&ldsXW[(nt * 16 + l16) * 72 + 32 + quad * 8];
#pragma unroll
            for (int s = 0; s < 2; s++) {
                acc[s][nt] = __builtin_amdgcn_mfma_f32_16x16x32_bf16(a0, pf[s][0], acc[s][nt], 0, 0, 0);
                acc[s][nt] = __builtin_amdgcn_mfma_f32_16x16x32_bf16(a1, pf[s][1], acc[s][nt], 0, 0, 0);
            }
        }

        __syncthreads();
        if (kt < 15) {
#pragma unroll
            for (int it = 0; it < 8; it++) {
                int idx = it * 256 + tid;
                int key = idx >> 5, col = (idx & 31) * 8;
                *(bf16x8*)&ldsK[key * 264 + col] = preK[it];
                int n = idx >> 3, kc = (idx & 7) * 8;
                *(bf16x8*)&ldsXW[n * 72 + kc] = preX[it];
            }
        }
        __syncthreads();
    }

    // store: acc[s][nt] holds D[n=nt*16+quad*4+r][q=q0+s*16+l16] -> b64 packs
    bf16* Ob = Opart + ((size_t)(ksp * B_ + b)) * L_ * E_;
#pragma unroll
    for (int s = 0; s < 2; s++) {
        size_t qrow = (size_t)(q0 + s * 16 + l16) * E_;
#pragma unroll
        for (int nt = 0; nt < 16; nt++) {
            bf16x4 pk;
#pragma unroll
            for (int r = 0; r < 4; r++) pk[r] = (bf16)acc[s][nt][r];
            *(bf16x4*)&Ob[qrow + nt * 16 + quad * 4] = pk;
        }
    }
}

// ---------------------------------------------------------------------------
// Kernel 5: sum the 2 k-split bf16 partials -> fp32 out[B,L,E]
// ---------------------------------------------------------------------------
__global__ void reduce_kernel(const bf16* __restrict__ Op, float* __restrict__ out) {
    size_t i = ((size_t)blockIdx.x * 256 + threadIdx.x) * 8;
    const size_t BLE = (size_t)B_ * L_ * E_;
    bf16x8 v0 = *(const bf16x8*)&Op[i];
    bf16x8 v1 = *(const bf16x8*)&Op[BLE + i];
    f32x4 o0, o1;
#pragma unroll
    for (int j = 0; j < 4; j++) o0[j] = (float)v0[j] + (float)v1[j];
#pragma unroll
    for (int j = 0; j < 4; j++) o1[j] = (float)v0[4 + j] + (float)v1[4 + j];
    *(f32x4*)&out[i] = o0;
    *(f32x4*)&out[i + 4] = o1;
}

// ---------------------------------------------------------------------------
extern "C" void kernel_launch(void* const* d_in, const int* in_sizes, int n_in,
                              void* d_out, int out_size, void* d_ws, size_t ws_size,
                              hipStream_t stream) {
    const float* x   = (const float*)d_in[0];
    const float* ipw = (const float*)d_in[1];
    const float* ipb = (const float*)d_in[2];
    const float* wg  = (const float*)d_in[3];
    const float* bg  = (const float*)d_in[4];

    char* ws = (char*)d_ws;
    // ws layout (bytes), total ~42.6 MB:
    //   Qs    [B,L,E]   bf16 @ 0          (8,388,608)
    //   Ks    [B,L,E]   bf16 @ 8388608    (8,388,608)
    //   XWT   [B,E,L]   bf16 @ 16777216   (8,388,608)
    //   o     [B,H,L]   f32  @ 25165824   (  262,144)
    //   Opart [2,B,L,E] bf16 @ 25427968   (16,777,216)
    //   Wcat  [768,256] bf16 @ 42205184   (  393,216)
    bf16*  Qs    = (bf16*)(ws);
    bf16*  Ks    = (bf16*)(ws + 8388608);
    bf16*  XWT   = (bf16*)(ws + 16777216);
    float* o     = (float*)(ws + 25165824);
    bf16*  Opart = (bf16*)(ws + 25427968);
    bf16*  Wcat  = (bf16*)(ws + 42205184);

    prep_weights<<<768, 256, 0, stream>>>(ipw, wg, Wcat);
    proj_kernel<<<256, 256, 0, stream>>>(x, Wcat, ipb, bg, Qs, Ks, XWT);
    stats_kernel<<<dim3(8, 4, 8), 256, 0, stream>>>(Qs, Ks, o);
    pass2_kernel<<<dim3(16, 2, 8), 256, 0, stream>>>(Qs, Ks, XWT, o, Opart);
    reduce_kernel<<<2048, 256, 0, stream>>>(Opart, (float*)d_out);
}